// Round 16
// baseline (172.395 us; speedup 1.0000x reference)
//
#include <hip/hip_runtime.h>

typedef unsigned short ushort_t;
typedef short bf16x8 __attribute__((ext_vector_type(8)));
typedef float f32x4 __attribute__((ext_vector_type(4)));
typedef float f32x16 __attribute__((ext_vector_type(16)));

__device__ __forceinline__ unsigned f2bf(float f) {
  union { float f; unsigned u; } v; v.f = f;
  return (v.u + 0x7FFFu + ((v.u >> 16) & 1u)) >> 16;
}

__device__ __forceinline__ void gll16(const void* g, const void* l) {
  __builtin_amdgcn_global_load_lds(
      (const __attribute__((address_space(1))) void*)g,
      (__attribute__((address_space(3))) void*)l, 16, 0, 0);
}

// ---------------- f32 -> bf16 conversion ----------------
__global__ __launch_bounds__(256) void cvt_bf16(const float* __restrict__ src,
                                                ushort_t* __restrict__ dst, int n4) {
  int i = blockIdx.x * 256 + threadIdx.x;
  if (i >= n4) return;
  float4 v = ((const float4*)src)[i];
  uint2 o;
  o.x = f2bf(v.x) | (f2bf(v.y) << 16);
  o.y = f2bf(v.z) | (f2bf(v.w) << 16);
  ((uint2*)dst)[i] = o;
}

// ---------------- QKV GEMM: C[8192][3072] = A[8192][1024] * W[3072][1024]^T ----
// Q columns (nt<8) are pre-scaled by 0.125*log2(e) so attention's softmax can
// use exp2(S) directly with no per-element fma (static softmax).
__global__ __launch_bounds__(256) void gemm_qkv(const ushort_t* __restrict__ A,
                                                const ushort_t* __restrict__ Bw,
                                                ushort_t* __restrict__ C) {
  __shared__ ushort_t As[128 * 64];
  __shared__ ushort_t Bs[128 * 64];
  const int tid = threadIdx.x;
  const int w = tid >> 6, ln = tid & 63;
  const int g = ln >> 4, lr = ln & 15;
  const int bx = blockIdx.x;
  const int nt = bx % 24, mt = bx / 24;
  const int m0 = mt * 128, n0 = nt * 128;
  const int wr = w >> 1, wc = w & 1;
  const float cscale = (nt < 8) ? 0.18033688f : 1.0f;  // Q pre-scale

  f32x4 acc[4][4] = {};

  for (int kt = 0; kt < 16; ++kt) {
#pragma unroll
    for (int q = 0; q < 4; ++q) {
      int chunk = w * 256 + q * 64 + ln;
      int r = chunk >> 3, c = chunk & 7;
      int cs = c ^ (r & 7);
      gll16(A + (size_t)(m0 + r) * 1024 + kt * 64 + cs * 8, As + chunk * 8);
      gll16(Bw + (size_t)(n0 + r) * 1024 + kt * 64 + cs * 8, Bs + chunk * 8);
    }
    __syncthreads();
#pragma unroll
    for (int ks = 0; ks < 2; ++ks) {
      bf16x8 af[4], bfr[4];
#pragma unroll
      for (int mi = 0; mi < 4; ++mi) {
        int row = wr * 64 + mi * 16 + lr;
        af[mi] = *(const bf16x8*)((const char*)As + row * 128 +
                                  ((g * 16 + ks * 64) ^ ((row & 7) << 4)));
      }
#pragma unroll
      for (int ni = 0; ni < 4; ++ni) {
        int row = wc * 64 + ni * 16 + lr;
        bfr[ni] = *(const bf16x8*)((const char*)Bs + row * 128 +
                                   ((g * 16 + ks * 64) ^ ((row & 7) << 4)));
      }
#pragma unroll
      for (int mi = 0; mi < 4; ++mi)
#pragma unroll
        for (int ni = 0; ni < 4; ++ni)
          acc[mi][ni] = __builtin_amdgcn_mfma_f32_16x16x32_bf16(af[mi], bfr[ni],
                                                                acc[mi][ni], 0, 0, 0);
    }
    __syncthreads();
  }

#pragma unroll
  for (int mi = 0; mi < 4; ++mi)
#pragma unroll
    for (int ni = 0; ni < 4; ++ni)
#pragma unroll
      for (int r = 0; r < 4; ++r) {
        int row = m0 + wr * 64 + mi * 16 + g * 4 + r;
        int col = n0 + wc * 64 + ni * 16 + lr;
        C[(size_t)row * 3072 + col] = (ushort_t)f2bf(acc[mi][ni][r] * cscale);
      }
}

// ---------------- V transpose: VT[bh*64+d][2048], kv order bit2<->bit3 swapped ----
__global__ __launch_bounds__(256) void vtrans(const ushort_t* __restrict__ qkv,
                                              ushort_t* __restrict__ VT) {
  __shared__ ushort_t tl[64][72];
  int blk = blockIdx.x;
  int bh = blk >> 5, nb = blk & 31;
  int b = bh >> 4, h = bh & 15;
  int t = threadIdx.x;
  int r = t >> 2, c = t & 3;
  const ushort_t* src = qkv + (size_t)(b * 2048 + nb * 64 + r) * 3072 + 2048 + h * 64 + c * 16;
  uint2 v0 = *(const uint2*)(src);
  uint2 v1 = *(const uint2*)(src + 4);
  uint2 v2 = *(const uint2*)(src + 8);
  uint2 v3 = *(const uint2*)(src + 12);
  *(uint2*)&tl[r][c * 16] = v0;
  *(uint2*)&tl[r][c * 16 + 4] = v1;
  *(uint2*)&tl[r][c * 16 + 8] = v2;
  *(uint2*)&tl[r][c * 16 + 12] = v3;
  __syncthreads();
  int d = t >> 2, dc = t & 3;
  unsigned pk[8];
#pragma unroll
  for (int j = 0; j < 8; ++j) {
    unsigned lo = tl[dc * 16 + 2 * j][d];
    unsigned hi = tl[dc * 16 + 2 * j + 1][d];
    pk[j] = lo | (hi << 16);
  }
  ushort_t* dst = VT + (size_t)(bh * 64 + d) * 2048 + nb * 64 + dc * 16;
  // bit2<->bit3 swapped dword order: {pk0,pk1,pk4,pk5}, {pk2,pk3,pk6,pk7}
  uint4 o0; o0.x = pk[0]; o0.y = pk[1]; o0.z = pk[4]; o0.w = pk[5];
  uint4 o1; o1.x = pk[2]; o1.y = pk[3]; o1.z = pk[6]; o1.w = pk[7];
  *(uint4*)dst = o0;
  *(uint4*)(dst + 8) = o1;
}

// One 32-kv subtile: QK^T -> exp2 -> VALU l-sum -> pack -> PV (r14-verified).
#define SUBTILE(KSB, VSB, LSOUT)                                              \
  {                                                                           \
    const ushort_t* KB = (KSB);                                               \
    const ushort_t* VB = (VSB);                                               \
    f32x16 S;                                                                 \
    _Pragma("unroll") for (int i = 0; i < 16; ++i) S[i] = 0.f;                \
    __builtin_amdgcn_s_setprio(1);                                            \
    _Pragma("unroll") for (int m = 0; m < 4; ++m) {                           \
      bf16x8 kf = *(const bf16x8*)(KB + q * 64 + (((2 * m + h) ^ qsw) * 8));  \
      S = __builtin_amdgcn_mfma_f32_32x32x16_bf16(kf, qf[m], S, 0, 0, 0);     \
    }                                                                         \
    __builtin_amdgcn_s_setprio(0);                                            \
    float p[16];                                                              \
    _Pragma("unroll") for (int i = 0; i < 16; ++i)                            \
      p[i] = __builtin_amdgcn_exp2f(S[i]);                                    \
    float s0 = (p[0] + p[1]) + (p[2] + p[3]);                                 \
    float s1 = (p[4] + p[5]) + (p[6] + p[7]);                                 \
    float s2 = (p[8] + p[9]) + (p[10] + p[11]);                               \
    float s3 = (p[12] + p[13]) + (p[14] + p[15]);                             \
    LSOUT = (s0 + s1) + (s2 + s3);                                            \
    union { unsigned u[4]; bf16x8 v; } pf0, pf1;                              \
    _Pragma("unroll") for (int i = 0; i < 4; ++i)                             \
      asm("v_cvt_pk_bf16_f32 %0, %1, %2"                                      \
          : "=v"(pf0.u[i]) : "v"(p[2 * i]), "v"(p[2 * i + 1]));               \
    _Pragma("unroll") for (int i = 0; i < 4; ++i)                             \
      asm("v_cvt_pk_bf16_f32 %0, %1, %2"                                      \
          : "=v"(pf1.u[i]) : "v"(p[8 + 2 * i]), "v"(p[8 + 2 * i + 1]));       \
    bf16x8 vf0 = *(const bf16x8*)(VB + q * 64 + (((0 + h) ^ qsw) * 8));       \
    bf16x8 vf1 = *(const bf16x8*)(VB + q * 64 + (((2 + h) ^ qsw) * 8));       \
    bf16x8 vf2 = *(const bf16x8*)(VB + q * 64 + (((4 + h) ^ qsw) * 8));       \
    bf16x8 vf3 = *(const bf16x8*)(VB + q * 64 + (((6 + h) ^ qsw) * 8));       \
    __builtin_amdgcn_s_setprio(1);                                            \
    oacc0 = __builtin_amdgcn_mfma_f32_32x32x16_bf16(vf0, pf0.v, oacc0, 0, 0, 0); \
    oacc0 = __builtin_amdgcn_mfma_f32_32x32x16_bf16(vf1, pf1.v, oacc0, 0, 0, 0); \
    oacc1 = __builtin_amdgcn_mfma_f32_32x32x16_bf16(vf2, pf0.v, oacc1, 0, 0, 0); \
    oacc1 = __builtin_amdgcn_mfma_f32_32x32x16_bf16(vf3, pf1.v, oacc1, 0, 0, 0); \
    __builtin_amdgcn_s_setprio(0);                                            \
  }

// ---------------- Flash attention: 512 threads, KVBLK=64, static softmax ------
// 8 waves compute 32 q each off a shared 64-kv tile; threads 0-255 stage K,
// 256-511 stage V, 2 chunks each per iter (two 32-row subtiles). 3-buffer
// counted protocol (r12 shape): stage tile t+2, compute t, vmcnt(2) at the
// barrier == tile t+1 resident. LDS 48 KB -> 3 blocks/CU = 24 waves/CU;
// barrier events halved vs KVBLK=32 (32 iters).
__global__ __launch_bounds__(512) void attn2(const ushort_t* __restrict__ qkv,
                                             const ushort_t* __restrict__ VT,
                                             float* __restrict__ out) {
  __shared__ ushort_t Ks[3][4096];   // [buf][2 subtiles x 32 rows x 64]
  __shared__ ushort_t Vs[3][4096];
  const int blk = blockIdx.x;
  // bh-major: all 8 q-tiles of one (b,h) share XCD (blk%8 const) -> K/V L2 reuse
  const int bh = blk & 63, qt = blk >> 6;
  const int b = bh >> 4, hh = bh & 15;
  const int tid = threadIdx.x;
  const int w = tid >> 6, l = tid & 63;
  const int q = l & 31, h = l >> 5;
  const int q0 = qt * 256 + w * 32;
  const int qsw = q & 7;

  // Q fragments (B-operand of swapped QK^T); Q pre-scaled by 0.125*log2(e)
  const ushort_t* qrow = qkv + (size_t)(b * 2048 + q0 + q) * 3072 + hh * 64 + 8 * h;
  bf16x8 qf[4];
#pragma unroll
  for (int m = 0; m < 4; ++m) qf[m] = *(const bf16x8*)(qrow + 16 * m);

  // staging: threads 0-255 carry K, 256-511 carry V; 2 chunks each per iter.
  const int st = tid & 255;
  const int rS = st >> 3, cS = st & 7;
  const int cL = cS ^ (rS & 7);
  const bool isK = tid < 256;
  const ushort_t* gsrc =
      isK ? qkv + (size_t)(b * 2048 + rS) * 3072 + 1024 + hh * 64 + cL * 8
          : VT + (size_t)(bh * 64 + rS + 32 * (cL >> 2)) * 2048 + (cL & 3) * 8;
  const size_t gstep = isK ? (size_t)64 * 3072 : (size_t)64;   // per 64-kv tile
  const size_t ghalf = isK ? (size_t)32 * 3072 : (size_t)32;   // subtile offset
  ushort_t* lbase = isK ? &Ks[0][0] : &Vs[0][0];  // + buf*4096 + {0,2048} + st*8

  f32x16 oacc0, oacc1;
#pragma unroll
  for (int i = 0; i < 16; ++i) { oacc0[i] = 0.f; oacc1[i] = 0.f; }
  float l_run = 0.f;

  // prologue: stage tiles 0 and 1 (2 loads/thread each)
  gll16(gsrc, lbase + st * 8);
  gll16(gsrc + ghalf, lbase + 2048 + st * 8);
  gll16(gsrc + gstep, lbase + 4096 + st * 8);
  gll16(gsrc + gstep + ghalf, lbase + 4096 + 2048 + st * 8);
  asm volatile("s_waitcnt vmcnt(2)" ::: "memory");
  __builtin_amdgcn_s_barrier();

  int cur = 0;
  for (int tt = 0; tt < 32; ++tt) {
    int tn = tt + 2; if (tn > 31) tn = 31;   // clamped prefetch (writes dead buffer)
    int bufn = cur + 2; if (bufn >= 3) bufn -= 3;
    gll16(gsrc + (size_t)tn * gstep, lbase + bufn * 4096 + st * 8);
    gll16(gsrc + (size_t)tn * gstep + ghalf, lbase + bufn * 4096 + 2048 + st * 8);

    float ls0, ls1;
    SUBTILE(Ks[cur], Vs[cur], ls0);
    SUBTILE(Ks[cur] + 2048, Vs[cur] + 2048, ls1);
    float ls = ls0 + ls1;
    ls += __shfl_xor(ls, 32, 64);
    l_run += ls;

    // tile t+1 resident when only this iter's 2 loads remain outstanding
    asm volatile("s_waitcnt vmcnt(2)" ::: "memory");
    __builtin_amdgcn_s_barrier();
    cur += 1; if (cur == 3) cur = 0;
  }

  // ---- epilogue: normalize by l, store O^T columns (16B chunks) ----
  float inv = 1.0f / l_run;
  float* orow = out + (size_t)(b * 2048 + q0 + q) * 1024 + hh * 64 + 4 * h;
#pragma unroll
  for (int rq = 0; rq < 4; ++rq) {
    float4 o0, o1;
    o0.x = oacc0[rq * 4 + 0] * inv; o0.y = oacc0[rq * 4 + 1] * inv;
    o0.z = oacc0[rq * 4 + 2] * inv; o0.w = oacc0[rq * 4 + 3] * inv;
    o1.x = oacc1[rq * 4 + 0] * inv; o1.y = oacc1[rq * 4 + 1] * inv;
    o1.z = oacc1[rq * 4 + 2] * inv; o1.w = oacc1[rq * 4 + 3] * inv;
    *(float4*)(orow + 8 * rq) = o0;
    *(float4*)(orow + 32 + 8 * rq) = o1;
  }
}

extern "C" void kernel_launch(void* const* d_in, const int* in_sizes, int n_in,
                              void* d_out, int out_size, void* d_ws, size_t ws_size,
                              hipStream_t stream) {
  const float* x = (const float*)d_in[0];
  const float* Wq = (const float*)d_in[1];
  float* out = (float*)d_out;
  char* ws = (char*)d_ws;

  ushort_t* xb = (ushort_t*)ws;                    // 16 MB: x bf16 [8192][1024]
  ushort_t* wb = (ushort_t*)(ws + 16777216);       // 6 MB:  W bf16 [3072][1024]
  ushort_t* qkv = (ushort_t*)(ws + 23068672);      // 48 MB: qkv bf16 [8192][3072]
  ushort_t* VT = xb;  // aliases xb (dead after GEMM): VT [64*64][2048]

  cvt_bf16<<<8192, 256, 0, stream>>>(x, xb, 8192 * 1024 / 4);
  cvt_bf16<<<3072, 256, 0, stream>>>(Wq, wb, 3072 * 1024 / 4);
  gemm_qkv<<<64 * 24, 256, 0, stream>>>(xb, wb, qkv);
  vtrans<<<64 * 32, 256, 0, stream>>>(qkv, VT);
  attn2<<<64 * 8, 512, 0, stream>>>(qkv, VT, out);
}

// Round 17
// 168.803 us; speedup vs baseline: 1.0213x; 1.0213x over previous
//
#include <hip/hip_runtime.h>

typedef unsigned short ushort_t;
typedef short bf16x8 __attribute__((ext_vector_type(8)));
typedef float f32x4 __attribute__((ext_vector_type(4)));
typedef float f32x16 __attribute__((ext_vector_type(16)));

__device__ __forceinline__ unsigned f2bf(float f) {
  union { float f; unsigned u; } v; v.f = f;
  return (v.u + 0x7FFFu + ((v.u >> 16) & 1u)) >> 16;
}

__device__ __forceinline__ void gll16(const void* g, const void* l) {
  __builtin_amdgcn_global_load_lds(
      (const __attribute__((address_space(1))) void*)g,
      (__attribute__((address_space(3))) void*)l, 16, 0, 0);
}

// ---------------- f32 -> bf16 conversion ----------------
__global__ __launch_bounds__(256) void cvt_bf16(const float* __restrict__ src,
                                                ushort_t* __restrict__ dst, int n4) {
  int i = blockIdx.x * 256 + threadIdx.x;
  if (i >= n4) return;
  float4 v = ((const float4*)src)[i];
  uint2 o;
  o.x = f2bf(v.x) | (f2bf(v.y) << 16);
  o.y = f2bf(v.z) | (f2bf(v.w) << 16);
  ((uint2*)dst)[i] = o;
}

// ---------------- QKV GEMM: C[8192][3072] = A[8192][1024] * W[3072][1024]^T ----
// Q columns (nt<8) are pre-scaled by 0.125*log2(e) (static softmax in attn).
// T1 XCD swizzle: swz=(bx&7)*192+(bx>>3) gives each XCD 8 contiguous mt-rows
// -> its 8 A-panels (2 MB) stay L2-resident instead of all XCDs refetching
// every A-panel (134 MB -> ~64 MB HBM fetch).
__global__ __launch_bounds__(256) void gemm_qkv(const ushort_t* __restrict__ A,
                                                const ushort_t* __restrict__ Bw,
                                                ushort_t* __restrict__ C) {
  __shared__ ushort_t As[128 * 64];
  __shared__ ushort_t Bs[128 * 64];
  const int tid = threadIdx.x;
  const int w = tid >> 6, ln = tid & 63;
  const int g = ln >> 4, lr = ln & 15;
  const int bx = blockIdx.x;
  const int swz = (bx & 7) * 192 + (bx >> 3);   // bijective (1536 % 8 == 0)
  const int nt = swz % 24, mt = swz / 24;
  const int m0 = mt * 128, n0 = nt * 128;
  const int wr = w >> 1, wc = w & 1;
  const float cscale = (nt < 8) ? 0.18033688f : 1.0f;  // Q pre-scale

  f32x4 acc[4][4] = {};

  for (int kt = 0; kt < 16; ++kt) {
#pragma unroll
    for (int q = 0; q < 4; ++q) {
      int chunk = w * 256 + q * 64 + ln;
      int r = chunk >> 3, c = chunk & 7;
      int cs = c ^ (r & 7);
      gll16(A + (size_t)(m0 + r) * 1024 + kt * 64 + cs * 8, As + chunk * 8);
      gll16(Bw + (size_t)(n0 + r) * 1024 + kt * 64 + cs * 8, Bs + chunk * 8);
    }
    __syncthreads();
#pragma unroll
    for (int ks = 0; ks < 2; ++ks) {
      bf16x8 af[4], bfr[4];
#pragma unroll
      for (int mi = 0; mi < 4; ++mi) {
        int row = wr * 64 + mi * 16 + lr;
        af[mi] = *(const bf16x8*)((const char*)As + row * 128 +
                                  ((g * 16 + ks * 64) ^ ((row & 7) << 4)));
      }
#pragma unroll
      for (int ni = 0; ni < 4; ++ni) {
        int row = wc * 64 + ni * 16 + lr;
        bfr[ni] = *(const bf16x8*)((const char*)Bs + row * 128 +
                                   ((g * 16 + ks * 64) ^ ((row & 7) << 4)));
      }
#pragma unroll
      for (int mi = 0; mi < 4; ++mi)
#pragma unroll
        for (int ni = 0; ni < 4; ++ni)
          acc[mi][ni] = __builtin_amdgcn_mfma_f32_16x16x32_bf16(af[mi], bfr[ni],
                                                                acc[mi][ni], 0, 0, 0);
    }
    __syncthreads();
  }

#pragma unroll
  for (int mi = 0; mi < 4; ++mi)
#pragma unroll
    for (int ni = 0; ni < 4; ++ni)
#pragma unroll
      for (int r = 0; r < 4; ++r) {
        int row = m0 + wr * 64 + mi * 16 + g * 4 + r;
        int col = n0 + wc * 64 + ni * 16 + lr;
        C[(size_t)row * 3072 + col] = (ushort_t)f2bf(acc[mi][ni][r] * cscale);
      }
}

// ---------------- V transpose: VT[bh*64+d][2048], kv order bit2<->bit3 swapped ----
__global__ __launch_bounds__(256) void vtrans(const ushort_t* __restrict__ qkv,
                                              ushort_t* __restrict__ VT) {
  __shared__ ushort_t tl[64][72];
  int blk = blockIdx.x;
  int bh = blk >> 5, nb = blk & 31;
  int b = bh >> 4, h = bh & 15;
  int t = threadIdx.x;
  int r = t >> 2, c = t & 3;
  const ushort_t* src = qkv + (size_t)(b * 2048 + nb * 64 + r) * 3072 + 2048 + h * 64 + c * 16;
  uint2 v0 = *(const uint2*)(src);
  uint2 v1 = *(const uint2*)(src + 4);
  uint2 v2 = *(const uint2*)(src + 8);
  uint2 v3 = *(const uint2*)(src + 12);
  *(uint2*)&tl[r][c * 16] = v0;
  *(uint2*)&tl[r][c * 16 + 4] = v1;
  *(uint2*)&tl[r][c * 16 + 8] = v2;
  *(uint2*)&tl[r][c * 16 + 12] = v3;
  __syncthreads();
  int d = t >> 2, dc = t & 3;
  unsigned pk[8];
#pragma unroll
  for (int j = 0; j < 8; ++j) {
    unsigned lo = tl[dc * 16 + 2 * j][d];
    unsigned hi = tl[dc * 16 + 2 * j + 1][d];
    pk[j] = lo | (hi << 16);
  }
  ushort_t* dst = VT + (size_t)(bh * 64 + d) * 2048 + nb * 64 + dc * 16;
  // bit2<->bit3 swapped dword order: {pk0,pk1,pk4,pk5}, {pk2,pk3,pk6,pk7}
  uint4 o0; o0.x = pk[0]; o0.y = pk[1]; o0.z = pk[4]; o0.w = pk[5];
  uint4 o1; o1.x = pk[2]; o1.y = pk[3]; o1.z = pk[6]; o1.w = pk[7];
  *(uint4*)dst = o0;
  *(uint4*)(dst + 8) = o1;
}

// ---------------- Flash attention, swapped-operand 32x32x16, static softmax ----
// r15 verbatim (best proven: 83 us). 512-thread blocks (8 waves): waves 0-3
// stage K, 4-7 stage V (1 gll16/thread/iter); all 8 waves compute 32 q each.
// r12 3-buffer counted protocol, vmcnt(1) at the barrier == tile t+1 resident.
__global__ __launch_bounds__(512) void attn2(const ushort_t* __restrict__ qkv,
                                             const ushort_t* __restrict__ VT,
                                             float* __restrict__ out) {
  __shared__ ushort_t Ks[3][2048];
  __shared__ ushort_t Vs[3][2048];
  const int blk = blockIdx.x;
  // bh-major: all 8 q-tiles of one (b,h) share XCD (blk%8 const) -> K/V L2 reuse
  const int bh = blk & 63, qt = blk >> 6;
  const int b = bh >> 4, hh = bh & 15;
  const int tid = threadIdx.x;
  const int w = tid >> 6, l = tid & 63;
  const int q = l & 31, h = l >> 5;
  const int q0 = qt * 256 + w * 32;
  const int qsw = q & 7;

  // Q fragments (B-operand of swapped QK^T); Q pre-scaled by 0.125*log2(e)
  const ushort_t* qrow = qkv + (size_t)(b * 2048 + q0 + q) * 3072 + hh * 64 + 8 * h;
  bf16x8 qf[4];
#pragma unroll
  for (int m = 0; m < 4; ++m) qf[m] = *(const bf16x8*)(qrow + 16 * m);

  // staging: threads 0-255 carry K, 256-511 carry V (wave-uniform split).
  const int st = tid & 255;
  const int rS = st >> 3, cS = st & 7;
  const int cL = cS ^ (rS & 7);
  const bool isK = tid < 256;
  const ushort_t* gsrc =
      isK ? qkv + (size_t)(b * 2048 + rS) * 3072 + 1024 + hh * 64 + cL * 8
          : VT + (size_t)(bh * 64 + rS + 32 * (cL >> 2)) * 2048 + (cL & 3) * 8;
  const size_t gstep = isK ? (size_t)32 * 3072 : (size_t)32;
  ushort_t* lbase = isK ? &Ks[0][0] : &Vs[0][0];  // + buf*2048 + st*8

  f32x16 oacc0, oacc1;
#pragma unroll
  for (int i = 0; i < 16; ++i) { oacc0[i] = 0.f; oacc1[i] = 0.f; }
  float l_run = 0.f;

  // prologue: stage tiles 0 and 1 (1 load/thread each)
  gll16(gsrc, lbase + st * 8);
  gll16(gsrc + gstep, lbase + 2048 + st * 8);
  asm volatile("s_waitcnt vmcnt(1)" ::: "memory");
  __builtin_amdgcn_s_barrier();

  int cur = 0;
  for (int t = 0; t < 64; ++t) {
    int tn = t + 2; if (tn > 63) tn = 63;          // clamped prefetch (writes dead buffer)
    int bufn = cur + 2; if (bufn >= 3) bufn -= 3;
    gll16(gsrc + (size_t)tn * gstep, lbase + bufn * 2048 + st * 8);

    const ushort_t* KsB = Ks[cur];
    const ushort_t* VsB = Vs[cur];

    // ---- QK^T (swapped): S^T[k][q], S pre-scaled via Q ----
    f32x16 S;
#pragma unroll
    for (int i = 0; i < 16; ++i) S[i] = 0.f;
    __builtin_amdgcn_s_setprio(1);
#pragma unroll
    for (int m = 0; m < 4; ++m) {
      bf16x8 kf = *(const bf16x8*)(KsB + q * 64 + (((2 * m + h) ^ qsw) * 8));
      S = __builtin_amdgcn_mfma_f32_32x32x16_bf16(kf, qf[m], S, 0, 0, 0);
    }
    __builtin_amdgcn_s_setprio(0);

    // ---- static softmax: p = exp2(S); l via VALU tree ----
    float p[16];
#pragma unroll
    for (int i = 0; i < 16; ++i) p[i] = __builtin_amdgcn_exp2f(S[i]);
    float s0 = (p[0] + p[1]) + (p[2] + p[3]);
    float s1 = (p[4] + p[5]) + (p[6] + p[7]);
    float s2 = (p[8] + p[9]) + (p[10] + p[11]);
    float s3 = (p[12] + p[13]) + (p[14] + p[15]);
    float ls = (s0 + s1) + (s2 + s3);
    ls += __shfl_xor(ls, 32, 64);
    l_run += ls;

    // ---- pack P to bf16 PV fragments: fully lane-local ----
    union { unsigned u[4]; bf16x8 v; } pf0, pf1;
#pragma unroll
    for (int i = 0; i < 4; ++i)
      asm("v_cvt_pk_bf16_f32 %0, %1, %2"
          : "=v"(pf0.u[i]) : "v"(p[2 * i]), "v"(p[2 * i + 1]));
#pragma unroll
    for (int i = 0; i < 4; ++i)
      asm("v_cvt_pk_bf16_f32 %0, %1, %2"
          : "=v"(pf1.u[i]) : "v"(p[8 + 2 * i]), "v"(p[8 + 2 * i + 1]));

    // ---- V fragments ----
    bf16x8 vf0 = *(const bf16x8*)(VsB + q * 64 + (((0 + h) ^ qsw) * 8));
    bf16x8 vf1 = *(const bf16x8*)(VsB + q * 64 + (((2 + h) ^ qsw) * 8));
    bf16x8 vf2 = *(const bf16x8*)(VsB + q * 64 + (((4 + h) ^ qsw) * 8));
    bf16x8 vf3 = *(const bf16x8*)(VsB + q * 64 + (((6 + h) ^ qsw) * 8));

    // ---- PV (swapped): O^T[d][q] += V^T[d][kv] * P^T[kv][q] ----
    __builtin_amdgcn_s_setprio(1);
    oacc0 = __builtin_amdgcn_mfma_f32_32x32x16_bf16(vf0, pf0.v, oacc0, 0, 0, 0);
    oacc0 = __builtin_amdgcn_mfma_f32_32x32x16_bf16(vf1, pf1.v, oacc0, 0, 0, 0);
    oacc1 = __builtin_amdgcn_mfma_f32_32x32x16_bf16(vf2, pf0.v, oacc1, 0, 0, 0);
    oacc1 = __builtin_amdgcn_mfma_f32_32x32x16_bf16(vf3, pf1.v, oacc1, 0, 0, 0);
    __builtin_amdgcn_s_setprio(0);

    // tile t+1 resident when the only outstanding load is this iter's (t+2)
    asm volatile("s_waitcnt vmcnt(1)" ::: "memory");
    __builtin_amdgcn_s_barrier();
    cur += 1; if (cur == 3) cur = 0;
  }

  // ---- epilogue: normalize by l, store O^T columns (16B chunks) ----
  float inv = 1.0f / l_run;
  float* orow = out + (size_t)(b * 2048 + q0 + q) * 1024 + hh * 64 + 4 * h;
#pragma unroll
  for (int rq = 0; rq < 4; ++rq) {
    float4 o0, o1;
    o0.x = oacc0[rq * 4 + 0] * inv; o0.y = oacc0[rq * 4 + 1] * inv;
    o0.z = oacc0[rq * 4 + 2] * inv; o0.w = oacc0[rq * 4 + 3] * inv;
    o1.x = oacc1[rq * 4 + 0] * inv; o1.y = oacc1[rq * 4 + 1] * inv;
    o1.z = oacc1[rq * 4 + 2] * inv; o1.w = oacc1[rq * 4 + 3] * inv;
    *(float4*)(orow + 8 * rq) = o0;
    *(float4*)(orow + 32 + 8 * rq) = o1;
  }
}

extern "C" void kernel_launch(void* const* d_in, const int* in_sizes, int n_in,
                              void* d_out, int out_size, void* d_ws, size_t ws_size,
                              hipStream_t stream) {
  const float* x = (const float*)d_in[0];
  const float* Wq = (const float*)d_in[1];
  float* out = (float*)d_out;
  char* ws = (char*)d_ws;

  ushort_t* xb = (ushort_t*)ws;                    // 16 MB: x bf16 [8192][1024]
  ushort_t* wb = (ushort_t*)(ws + 16777216);       // 6 MB:  W bf16 [3072][1024]
  ushort_t* qkv = (ushort_t*)(ws + 23068672);      // 48 MB: qkv bf16 [8192][3072]
  ushort_t* VT = xb;  // aliases xb (dead after GEMM): VT [64*64][2048]

  cvt_bf16<<<8192, 256, 0, stream>>>(x, xb, 8192 * 1024 / 4);
  cvt_bf16<<<3072, 256, 0, stream>>>(Wq, wb, 3072 * 1024 / 4);
  gemm_qkv<<<64 * 24, 256, 0, stream>>>(xb, wb, qkv);
  vtrans<<<64 * 32, 256, 0, stream>>>(qkv, VT);
  attn2<<<64 * 8, 512, 0, stream>>>(qkv, VT, out);
}

// Round 18
// 168.020 us; speedup vs baseline: 1.0260x; 1.0047x over previous
//
#include <hip/hip_runtime.h>

typedef unsigned short ushort_t;
typedef short bf16x8 __attribute__((ext_vector_type(8)));
typedef float f32x4 __attribute__((ext_vector_type(4)));
typedef float f32x16 __attribute__((ext_vector_type(16)));

__device__ __forceinline__ unsigned f2bf(float f) {
  union { float f; unsigned u; } v; v.f = f;
  return (v.u + 0x7FFFu + ((v.u >> 16) & 1u)) >> 16;
}

__device__ __forceinline__ void gll16(const void* g, const void* l) {
  __builtin_amdgcn_global_load_lds(
      (const __attribute__((address_space(1))) void*)g,
      (__attribute__((address_space(3))) void*)l, 16, 0, 0);
}

// ---------------- f32 -> bf16 conversion ----------------
__global__ __launch_bounds__(256) void cvt_bf16(const float* __restrict__ src,
                                                ushort_t* __restrict__ dst, int n4) {
  int i = blockIdx.x * 256 + threadIdx.x;
  if (i >= n4) return;
  float4 v = ((const float4*)src)[i];
  uint2 o;
  o.x = f2bf(v.x) | (f2bf(v.y) << 16);
  o.y = f2bf(v.z) | (f2bf(v.w) << 16);
  ((uint2*)dst)[i] = o;
}

// ---------------- QKV GEMM + fused V-transpose ----------------
// C = A[8192][1024] * W[3072][1024]^T. Q/K thirds (nt<16) -> qk[8192][2048]
// (Q pre-scaled by 0.125*log2(e) for the static softmax). V third (nt>=16)
// is written DIRECTLY to VT[bh*64+d][2048] with the kv bit2<->3 permutation
// (vtrans kernel eliminated). Block swizzle: 8 contiguous mt-rows per XCD.
__global__ __launch_bounds__(256) void gemm_qkv(const ushort_t* __restrict__ A,
                                                const ushort_t* __restrict__ Bw,
                                                ushort_t* __restrict__ qk,
                                                ushort_t* __restrict__ VT) {
  __shared__ ushort_t As[128 * 64];
  __shared__ ushort_t Bs[128 * 64];
  const int tid = threadIdx.x;
  const int w = tid >> 6, ln = tid & 63;
  const int g = ln >> 4, lr = ln & 15;
  const int bx = blockIdx.x;
  const int swz = (bx & 7) * 192 + (bx >> 3);   // bijective (1536 % 8 == 0)
  const int nt = swz % 24, mt = swz / 24;
  const int m0 = mt * 128, n0 = nt * 128;
  const int wr = w >> 1, wc = w & 1;
  const float cscale = (nt < 8) ? 0.18033688f : 1.0f;  // Q pre-scale

  f32x4 acc[4][4] = {};

  for (int kt = 0; kt < 16; ++kt) {
#pragma unroll
    for (int q = 0; q < 4; ++q) {
      int chunk = w * 256 + q * 64 + ln;
      int r = chunk >> 3, c = chunk & 7;
      int cs = c ^ (r & 7);
      gll16(A + (size_t)(m0 + r) * 1024 + kt * 64 + cs * 8, As + chunk * 8);
      gll16(Bw + (size_t)(n0 + r) * 1024 + kt * 64 + cs * 8, Bs + chunk * 8);
    }
    __syncthreads();
#pragma unroll
    for (int ks = 0; ks < 2; ++ks) {
      bf16x8 af[4], bfr[4];
#pragma unroll
      for (int mi = 0; mi < 4; ++mi) {
        int row = wr * 64 + mi * 16 + lr;
        af[mi] = *(const bf16x8*)((const char*)As + row * 128 +
                                  ((g * 16 + ks * 64) ^ ((row & 7) << 4)));
      }
#pragma unroll
      for (int ni = 0; ni < 4; ++ni) {
        int row = wc * 64 + ni * 16 + lr;
        bfr[ni] = *(const bf16x8*)((const char*)Bs + row * 128 +
                                   ((g * 16 + ks * 64) ^ ((row & 7) << 4)));
      }
#pragma unroll
      for (int mi = 0; mi < 4; ++mi)
#pragma unroll
        for (int ni = 0; ni < 4; ++ni)
          acc[mi][ni] = __builtin_amdgcn_mfma_f32_16x16x32_bf16(af[mi], bfr[ni],
                                                                acc[mi][ni], 0, 0, 0);
    }
    __syncthreads();
  }

  if (nt < 16) {
    // Q/K: plain row-major write into qk[8192][2048]
#pragma unroll
    for (int mi = 0; mi < 4; ++mi)
#pragma unroll
      for (int ni = 0; ni < 4; ++ni)
#pragma unroll
        for (int r = 0; r < 4; ++r) {
          int row = m0 + wr * 64 + mi * 16 + g * 4 + r;
          int col = n0 + wc * 64 + ni * 16 + lr;
          qk[(size_t)row * 2048 + col] = (ushort_t)f2bf(acc[mi][ni][r] * cscale);
        }
  } else {
    // V: fused transpose to VT[(b*16+hh)*64+d][2048], token bits 2<->3 swapped.
    // tokens g*4+r (r=0..3) stay contiguous under the swap (g -> g').
    const int b = m0 >> 11;               // block's 128 tokens lie in one b
    const int gp = ((g & 1) << 1) | (g >> 1);   // swap the two bits of g
#pragma unroll
    for (int mi = 0; mi < 4; ++mi) {
      int nbase = (m0 & 2047) + wr * 64 + mi * 16 + gp * 4;
#pragma unroll
      for (int ni = 0; ni < 4; ++ni) {
        int f = n0 - 2048 + wc * 64 + ni * 16 + lr;  // v-feature 0..1023
        int hh = f >> 6, d = f & 63;
        uint2 o;
        o.x = f2bf(acc[mi][ni][0]) | (f2bf(acc[mi][ni][1]) << 16);
        o.y = f2bf(acc[mi][ni][2]) | (f2bf(acc[mi][ni][3]) << 16);
        *(uint2*)(VT + ((size_t)(b * 16 + hh) * 64 + d) * 2048 + nbase) = o;
      }
    }
  }
}

// ---------------- Flash attention, swapped-operand 32x32x16, static softmax ----
// r15 structure (best proven). Changes: QK uses two independent accumulators
// (Sa,Sb) to halve the dependent-MFMA chain latency; l cross-half shfl hoisted
// out of the loop (linearity). K read from qk[.][2048] (stride change only).
__global__ __launch_bounds__(512) void attn2(const ushort_t* __restrict__ qk,
                                             const ushort_t* __restrict__ VT,
                                             float* __restrict__ out) {
  __shared__ ushort_t Ks[3][2048];
  __shared__ ushort_t Vs[3][2048];
  const int blk = blockIdx.x;
  // bh-major: all 8 q-tiles of one (b,h) share XCD (blk%8 const) -> K/V L2 reuse
  const int bh = blk & 63, qt = blk >> 6;
  const int b = bh >> 4, hh = bh & 15;
  const int tid = threadIdx.x;
  const int w = tid >> 6, l = tid & 63;
  const int q = l & 31, h = l >> 5;
  const int q0 = qt * 256 + w * 32;
  const int qsw = q & 7;

  // Q fragments (B-operand of swapped QK^T); Q pre-scaled by 0.125*log2(e)
  const ushort_t* qrow = qk + (size_t)(b * 2048 + q0 + q) * 2048 + hh * 64 + 8 * h;
  bf16x8 qf[4];
#pragma unroll
  for (int m = 0; m < 4; ++m) qf[m] = *(const bf16x8*)(qrow + 16 * m);

  // staging: threads 0-255 carry K, 256-511 carry V (wave-uniform split).
  const int st = tid & 255;
  const int rS = st >> 3, cS = st & 7;
  const int cL = cS ^ (rS & 7);
  const bool isK = tid < 256;
  const ushort_t* gsrc =
      isK ? qk + (size_t)(b * 2048 + rS) * 2048 + 1024 + hh * 64 + cL * 8
          : VT + (size_t)(bh * 64 + rS + 32 * (cL >> 2)) * 2048 + (cL & 3) * 8;
  const size_t gstep = isK ? (size_t)32 * 2048 : (size_t)32;
  ushort_t* lbase = isK ? &Ks[0][0] : &Vs[0][0];  // + buf*2048 + st*8

  f32x16 oacc0, oacc1;
#pragma unroll
  for (int i = 0; i < 16; ++i) { oacc0[i] = 0.f; oacc1[i] = 0.f; }
  float l_run = 0.f;

  // prologue: stage tiles 0 and 1 (1 load/thread each)
  gll16(gsrc, lbase + st * 8);
  gll16(gsrc + gstep, lbase + 2048 + st * 8);
  asm volatile("s_waitcnt vmcnt(1)" ::: "memory");
  __builtin_amdgcn_s_barrier();

  int cur = 0;
  for (int t = 0; t < 64; ++t) {
    int tn = t + 2; if (tn > 63) tn = 63;          // clamped prefetch (writes dead buffer)
    int bufn = cur + 2; if (bufn >= 3) bufn -= 3;
    gll16(gsrc + (size_t)tn * gstep, lbase + bufn * 2048 + st * 8);

    const ushort_t* KsB = Ks[cur];
    const ushort_t* VsB = Vs[cur];

    // ---- QK^T (swapped), two independent accumulator chains ----
    f32x16 Sa, Sb;
#pragma unroll
    for (int i = 0; i < 16; ++i) { Sa[i] = 0.f; Sb[i] = 0.f; }
    __builtin_amdgcn_s_setprio(1);
    {
      bf16x8 kf0 = *(const bf16x8*)(KsB + q * 64 + (((0 + h) ^ qsw) * 8));
      bf16x8 kf1 = *(const bf16x8*)(KsB + q * 64 + (((2 + h) ^ qsw) * 8));
      bf16x8 kf2 = *(const bf16x8*)(KsB + q * 64 + (((4 + h) ^ qsw) * 8));
      bf16x8 kf3 = *(const bf16x8*)(KsB + q * 64 + (((6 + h) ^ qsw) * 8));
      Sa = __builtin_amdgcn_mfma_f32_32x32x16_bf16(kf0, qf[0], Sa, 0, 0, 0);
      Sb = __builtin_amdgcn_mfma_f32_32x32x16_bf16(kf2, qf[2], Sb, 0, 0, 0);
      Sa = __builtin_amdgcn_mfma_f32_32x32x16_bf16(kf1, qf[1], Sa, 0, 0, 0);
      Sb = __builtin_amdgcn_mfma_f32_32x32x16_bf16(kf3, qf[3], Sb, 0, 0, 0);
    }
    __builtin_amdgcn_s_setprio(0);

    // ---- static softmax: p = exp2(Sa+Sb); l accumulated lane-locally ----
    float p[16];
#pragma unroll
    for (int i = 0; i < 16; ++i) p[i] = __builtin_amdgcn_exp2f(Sa[i] + Sb[i]);
    float s0 = (p[0] + p[1]) + (p[2] + p[3]);
    float s1 = (p[4] + p[5]) + (p[6] + p[7]);
    float s2 = (p[8] + p[9]) + (p[10] + p[11]);
    float s3 = (p[12] + p[13]) + (p[14] + p[15]);
    l_run += (s0 + s1) + (s2 + s3);

    // ---- pack P to bf16 PV fragments: fully lane-local ----
    union { unsigned u[4]; bf16x8 v; } pf0, pf1;
#pragma unroll
    for (int i = 0; i < 4; ++i)
      asm("v_cvt_pk_bf16_f32 %0, %1, %2"
          : "=v"(pf0.u[i]) : "v"(p[2 * i]), "v"(p[2 * i + 1]));
#pragma unroll
    for (int i = 0; i < 4; ++i)
      asm("v_cvt_pk_bf16_f32 %0, %1, %2"
          : "=v"(pf1.u[i]) : "v"(p[8 + 2 * i]), "v"(p[8 + 2 * i + 1]));

    // ---- V fragments ----
    bf16x8 vf0 = *(const bf16x8*)(VsB + q * 64 + (((0 + h) ^ qsw) * 8));
    bf16x8 vf1 = *(const bf16x8*)(VsB + q * 64 + (((2 + h) ^ qsw) * 8));
    bf16x8 vf2 = *(const bf16x8*)(VsB + q * 64 + (((4 + h) ^ qsw) * 8));
    bf16x8 vf3 = *(const bf16x8*)(VsB + q * 64 + (((6 + h) ^ qsw) * 8));

    // ---- PV (swapped): O^T[d][q] += V^T[d][kv] * P^T[kv][q] ----
    __builtin_amdgcn_s_setprio(1);
    oacc0 = __builtin_amdgcn_mfma_f32_32x32x16_bf16(vf0, pf0.v, oacc0, 0, 0, 0);
    oacc1 = __builtin_amdgcn_mfma_f32_32x32x16_bf16(vf2, pf0.v, oacc1, 0, 0, 0);
    oacc0 = __builtin_amdgcn_mfma_f32_32x32x16_bf16(vf1, pf1.v, oacc0, 0, 0, 0);
    oacc1 = __builtin_amdgcn_mfma_f32_32x32x16_bf16(vf3, pf1.v, oacc1, 0, 0, 0);
    __builtin_amdgcn_s_setprio(0);

    // tile t+1 resident when the only outstanding load is this iter's (t+2)
    asm volatile("s_waitcnt vmcnt(1)" ::: "memory");
    __builtin_amdgcn_s_barrier();
    cur += 1; if (cur == 3) cur = 0;
  }

  // ---- epilogue: merge l halves once, normalize, store O^T columns ----
  l_run += __shfl_xor(l_run, 32, 64);
  float inv = 1.0f / l_run;
  float* orow = out + (size_t)(b * 2048 + q0 + q) * 1024 + hh * 64 + 4 * h;
#pragma unroll
  for (int rq = 0; rq < 4; ++rq) {
    float4 o0, o1;
    o0.x = oacc0[rq * 4 + 0] * inv; o0.y = oacc0[rq * 4 + 1] * inv;
    o0.z = oacc0[rq * 4 + 2] * inv; o0.w = oacc0[rq * 4 + 3] * inv;
    o1.x = oacc1[rq * 4 + 0] * inv; o1.y = oacc1[rq * 4 + 1] * inv;
    o1.z = oacc1[rq * 4 + 2] * inv; o1.w = oacc1[rq * 4 + 3] * inv;
    *(float4*)(orow + 8 * rq) = o0;
    *(float4*)(orow + 32 + 8 * rq) = o1;
  }
}

extern "C" void kernel_launch(void* const* d_in, const int* in_sizes, int n_in,
                              void* d_out, int out_size, void* d_ws, size_t ws_size,
                              hipStream_t stream) {
  const float* x = (const float*)d_in[0];
  const float* Wq = (const float*)d_in[1];
  float* out = (float*)d_out;
  char* ws = (char*)d_ws;

  ushort_t* xb = (ushort_t*)ws;                      // 16 MB: x bf16 [8192][1024]
  ushort_t* wb = (ushort_t*)(ws + 16777216);         // 6 MB:  W bf16 [3072][1024]
  ushort_t* qk = (ushort_t*)(ws + 23068672);         // 32 MB: Q|K bf16 [8192][2048]
  ushort_t* VT = (ushort_t*)(ws + 23068672 + 33554432);  // 16 MB: VT [64*64][2048]

  cvt_bf16<<<8192, 256, 0, stream>>>(x, xb, 8192 * 1024 / 4);
  cvt_bf16<<<3072, 256, 0, stream>>>(Wq, wb, 3072 * 1024 / 4);
  gemm_qkv<<<64 * 24, 256, 0, stream>>>(xb, wb, qk, VT);
  attn2<<<64 * 8, 512, 0, stream>>>(qk, VT, out);
}

// Round 19
// 164.710 us; speedup vs baseline: 1.0467x; 1.0201x over previous
//
#include <hip/hip_runtime.h>

typedef unsigned short ushort_t;
typedef short bf16x8 __attribute__((ext_vector_type(8)));
typedef float f32x4 __attribute__((ext_vector_type(4)));
typedef float f32x16 __attribute__((ext_vector_type(16)));

__device__ __forceinline__ unsigned f2bf(float f) {
  union { float f; unsigned u; } v; v.f = f;
  return (v.u + 0x7FFFu + ((v.u >> 16) & 1u)) >> 16;
}

__device__ __forceinline__ void gll16(const void* g, const void* l) {
  __builtin_amdgcn_global_load_lds(
      (const __attribute__((address_space(1))) void*)g,
      (__attribute__((address_space(3))) void*)l, 16, 0, 0);
}

// ---------------- f32 -> bf16 conversion ----------------
__global__ __launch_bounds__(256) void cvt_bf16(const float* __restrict__ src,
                                                ushort_t* __restrict__ dst, int n4) {
  int i = blockIdx.x * 256 + threadIdx.x;
  if (i >= n4) return;
  float4 v = ((const float4*)src)[i];
  uint2 o;
  o.x = f2bf(v.x) | (f2bf(v.y) << 16);
  o.y = f2bf(v.z) | (f2bf(v.w) << 16);
  ((uint2*)dst)[i] = o;
}

// ---------------- QKV GEMM + fused V-transpose ----------------
// C = A[8192][1024] * W[3072][1024]^T. Q/K thirds (nt<16) -> qk[8192][2048]
// (Q pre-scaled by 0.125*log2(e) for the static softmax). V third (nt>=16)
// is written DIRECTLY to VT[bh*64+d][2048] with the kv bit2<->3 permutation
// (vtrans kernel eliminated). Block swizzle: 8 contiguous mt-rows per XCD.
__global__ __launch_bounds__(256) void gemm_qkv(const ushort_t* __restrict__ A,
                                                const ushort_t* __restrict__ Bw,
                                                ushort_t* __restrict__ qk,
                                                ushort_t* __restrict__ VT) {
  __shared__ ushort_t As[128 * 64];
  __shared__ ushort_t Bs[128 * 64];
  const int tid = threadIdx.x;
  const int w = tid >> 6, ln = tid & 63;
  const int g = ln >> 4, lr = ln & 15;
  const int bx = blockIdx.x;
  const int swz = (bx & 7) * 192 + (bx >> 3);   // bijective (1536 % 8 == 0)
  const int nt = swz % 24, mt = swz / 24;
  const int m0 = mt * 128, n0 = nt * 128;
  const int wr = w >> 1, wc = w & 1;
  const float cscale = (nt < 8) ? 0.18033688f : 1.0f;  // Q pre-scale

  f32x4 acc[4][4] = {};

  for (int kt = 0; kt < 16; ++kt) {
#pragma unroll
    for (int q = 0; q < 4; ++q) {
      int chunk = w * 256 + q * 64 + ln;
      int r = chunk >> 3, c = chunk & 7;
      int cs = c ^ (r & 7);
      gll16(A + (size_t)(m0 + r) * 1024 + kt * 64 + cs * 8, As + chunk * 8);
      gll16(Bw + (size_t)(n0 + r) * 1024 + kt * 64 + cs * 8, Bs + chunk * 8);
    }
    __syncthreads();
#pragma unroll
    for (int ks = 0; ks < 2; ++ks) {
      bf16x8 af[4], bfr[4];
#pragma unroll
      for (int mi = 0; mi < 4; ++mi) {
        int row = wr * 64 + mi * 16 + lr;
        af[mi] = *(const bf16x8*)((const char*)As + row * 128 +
                                  ((g * 16 + ks * 64) ^ ((row & 7) << 4)));
      }
#pragma unroll
      for (int ni = 0; ni < 4; ++ni) {
        int row = wc * 64 + ni * 16 + lr;
        bfr[ni] = *(const bf16x8*)((const char*)Bs + row * 128 +
                                   ((g * 16 + ks * 64) ^ ((row & 7) << 4)));
      }
#pragma unroll
      for (int mi = 0; mi < 4; ++mi)
#pragma unroll
        for (int ni = 0; ni < 4; ++ni)
          acc[mi][ni] = __builtin_amdgcn_mfma_f32_16x16x32_bf16(af[mi], bfr[ni],
                                                                acc[mi][ni], 0, 0, 0);
    }
    __syncthreads();
  }

  if (nt < 16) {
    // Q/K: plain row-major write into qk[8192][2048]
#pragma unroll
    for (int mi = 0; mi < 4; ++mi)
#pragma unroll
      for (int ni = 0; ni < 4; ++ni)
#pragma unroll
        for (int r = 0; r < 4; ++r) {
          int row = m0 + wr * 64 + mi * 16 + g * 4 + r;
          int col = n0 + wc * 64 + ni * 16 + lr;
          qk[(size_t)row * 2048 + col] = (ushort_t)f2bf(acc[mi][ni][r] * cscale);
        }
  } else {
    // V: fused transpose to VT[(b*16+hh)*64+d][2048], token bits 2<->3 swapped.
    const int b = m0 >> 11;               // block's 128 tokens lie in one b
    const int gp = ((g & 1) << 1) | (g >> 1);   // swap the two bits of g
#pragma unroll
    for (int mi = 0; mi < 4; ++mi) {
      int nbase = (m0 & 2047) + wr * 64 + mi * 16 + gp * 4;
#pragma unroll
      for (int ni = 0; ni < 4; ++ni) {
        int f = n0 - 2048 + wc * 64 + ni * 16 + lr;  // v-feature 0..1023
        int hh = f >> 6, d = f & 63;
        uint2 o;
        o.x = f2bf(acc[mi][ni][0]) | (f2bf(acc[mi][ni][1]) << 16);
        o.y = f2bf(acc[mi][ni][2]) | (f2bf(acc[mi][ni][3]) << 16);
        *(uint2*)(VT + ((size_t)(b * 16 + hh) * 64 + d) * 2048 + nbase) = o;
      }
    }
  }
}

// ---------------- Flash attention, swapped-operand 32x32x16, static softmax ----
// r15/r17-proven body verbatim (single S chain, in-loop l shfl). 512-thread
// blocks: waves 0-3 stage K, 4-7 stage V (1 gll16/thread/iter); 8 waves x 32 q.
// r12 3-buffer counted protocol, vmcnt(1) at barrier == tile t+1 resident.
__global__ __launch_bounds__(512) void attn2(const ushort_t* __restrict__ qk,
                                             const ushort_t* __restrict__ VT,
                                             float* __restrict__ out) {
  __shared__ ushort_t Ks[3][2048];
  __shared__ ushort_t Vs[3][2048];
  const int blk = blockIdx.x;
  // bh-major: all 8 q-tiles of one (b,h) share XCD (blk%8 const) -> K/V L2 reuse
  const int bh = blk & 63, qt = blk >> 6;
  const int b = bh >> 4, hh = bh & 15;
  const int tid = threadIdx.x;
  const int w = tid >> 6, l = tid & 63;
  const int q = l & 31, h = l >> 5;
  const int q0 = qt * 256 + w * 32;
  const int qsw = q & 7;

  // Q fragments (B-operand of swapped QK^T); Q pre-scaled by 0.125*log2(e)
  const ushort_t* qrow = qk + (size_t)(b * 2048 + q0 + q) * 2048 + hh * 64 + 8 * h;
  bf16x8 qf[4];
#pragma unroll
  for (int m = 0; m < 4; ++m) qf[m] = *(const bf16x8*)(qrow + 16 * m);

  // staging: threads 0-255 carry K, 256-511 carry V (wave-uniform split).
  const int st = tid & 255;
  const int rS = st >> 3, cS = st & 7;
  const int cL = cS ^ (rS & 7);
  const bool isK = tid < 256;
  const ushort_t* gsrc =
      isK ? qk + (size_t)(b * 2048 + rS) * 2048 + 1024 + hh * 64 + cL * 8
          : VT + (size_t)(bh * 64 + rS + 32 * (cL >> 2)) * 2048 + (cL & 3) * 8;
  const size_t gstep = isK ? (size_t)32 * 2048 : (size_t)32;
  ushort_t* lbase = isK ? &Ks[0][0] : &Vs[0][0];  // + buf*2048 + st*8

  f32x16 oacc0, oacc1;
#pragma unroll
  for (int i = 0; i < 16; ++i) { oacc0[i] = 0.f; oacc1[i] = 0.f; }
  float l_run = 0.f;

  // prologue: stage tiles 0 and 1 (1 load/thread each)
  gll16(gsrc, lbase + st * 8);
  gll16(gsrc + gstep, lbase + 2048 + st * 8);
  asm volatile("s_waitcnt vmcnt(1)" ::: "memory");
  __builtin_amdgcn_s_barrier();

  int cur = 0;
  for (int t = 0; t < 64; ++t) {
    int tn = t + 2; if (tn > 63) tn = 63;          // clamped prefetch (writes dead buffer)
    int bufn = cur + 2; if (bufn >= 3) bufn -= 3;
    gll16(gsrc + (size_t)tn * gstep, lbase + bufn * 2048 + st * 8);

    const ushort_t* KsB = Ks[cur];
    const ushort_t* VsB = Vs[cur];

    // ---- QK^T (swapped): S^T[k][q], S pre-scaled via Q ----
    f32x16 S;
#pragma unroll
    for (int i = 0; i < 16; ++i) S[i] = 0.f;
    __builtin_amdgcn_s_setprio(1);
#pragma unroll
    for (int m = 0; m < 4; ++m) {
      bf16x8 kf = *(const bf16x8*)(KsB + q * 64 + (((2 * m + h) ^ qsw) * 8));
      S = __builtin_amdgcn_mfma_f32_32x32x16_bf16(kf, qf[m], S, 0, 0, 0);
    }
    __builtin_amdgcn_s_setprio(0);

    // ---- static softmax: p = exp2(S); l via VALU tree ----
    float p[16];
#pragma unroll
    for (int i = 0; i < 16; ++i) p[i] = __builtin_amdgcn_exp2f(S[i]);
    float s0 = (p[0] + p[1]) + (p[2] + p[3]);
    float s1 = (p[4] + p[5]) + (p[6] + p[7]);
    float s2 = (p[8] + p[9]) + (p[10] + p[11]);
    float s3 = (p[12] + p[13]) + (p[14] + p[15]);
    float ls = (s0 + s1) + (s2 + s3);
    ls += __shfl_xor(ls, 32, 64);
    l_run += ls;

    // ---- pack P to bf16 PV fragments: fully lane-local ----
    union { unsigned u[4]; bf16x8 v; } pf0, pf1;
#pragma unroll
    for (int i = 0; i < 4; ++i)
      asm("v_cvt_pk_bf16_f32 %0, %1, %2"
          : "=v"(pf0.u[i]) : "v"(p[2 * i]), "v"(p[2 * i + 1]));
#pragma unroll
    for (int i = 0; i < 4; ++i)
      asm("v_cvt_pk_bf16_f32 %0, %1, %2"
          : "=v"(pf1.u[i]) : "v"(p[8 + 2 * i]), "v"(p[8 + 2 * i + 1]));

    // ---- V fragments ----
    bf16x8 vf0 = *(const bf16x8*)(VsB + q * 64 + (((0 + h) ^ qsw) * 8));
    bf16x8 vf1 = *(const bf16x8*)(VsB + q * 64 + (((2 + h) ^ qsw) * 8));
    bf16x8 vf2 = *(const bf16x8*)(VsB + q * 64 + (((4 + h) ^ qsw) * 8));
    bf16x8 vf3 = *(const bf16x8*)(VsB + q * 64 + (((6 + h) ^ qsw) * 8));

    // ---- PV (swapped): O^T[d][q] += V^T[d][kv] * P^T[kv][q] ----
    __builtin_amdgcn_s_setprio(1);
    oacc0 = __builtin_amdgcn_mfma_f32_32x32x16_bf16(vf0, pf0.v, oacc0, 0, 0, 0);
    oacc0 = __builtin_amdgcn_mfma_f32_32x32x16_bf16(vf1, pf1.v, oacc0, 0, 0, 0);
    oacc1 = __builtin_amdgcn_mfma_f32_32x32x16_bf16(vf2, pf0.v, oacc1, 0, 0, 0);
    oacc1 = __builtin_amdgcn_mfma_f32_32x32x16_bf16(vf3, pf1.v, oacc1, 0, 0, 0);
    __builtin_amdgcn_s_setprio(0);

    // tile t+1 resident when the only outstanding load is this iter's (t+2)
    asm volatile("s_waitcnt vmcnt(1)" ::: "memory");
    __builtin_amdgcn_s_barrier();
    cur += 1; if (cur == 3) cur = 0;
  }

  // ---- epilogue: normalize by l, store O^T columns (16B chunks) ----
  float inv = 1.0f / l_run;
  float* orow = out + (size_t)(b * 2048 + q0 + q) * 1024 + hh * 64 + 4 * h;
#pragma unroll
  for (int rq = 0; rq < 4; ++rq) {
    float4 o0, o1;
    o0.x = oacc0[rq * 4 + 0] * inv; o0.y = oacc0[rq * 4 + 1] * inv;
    o0.z = oacc0[rq * 4 + 2] * inv; o0.w = oacc0[rq * 4 + 3] * inv;
    o1.x = oacc1[rq * 4 + 0] * inv; o1.y = oacc1[rq * 4 + 1] * inv;
    o1.z = oacc1[rq * 4 + 2] * inv; o1.w = oacc1[rq * 4 + 3] * inv;
    *(float4*)(orow + 8 * rq) = o0;
    *(float4*)(orow + 32 + 8 * rq) = o1;
  }
}

extern "C" void kernel_launch(void* const* d_in, const int* in_sizes, int n_in,
                              void* d_out, int out_size, void* d_ws, size_t ws_size,
                              hipStream_t stream) {
  const float* x = (const float*)d_in[0];
  const float* Wq = (const float*)d_in[1];
  float* out = (float*)d_out;
  char* ws = (char*)d_ws;

  ushort_t* xb = (ushort_t*)ws;                      // 16 MB: x bf16 [8192][1024]
  ushort_t* wb = (ushort_t*)(ws + 16777216);         // 6 MB:  W bf16 [3072][1024]
  ushort_t* qk = (ushort_t*)(ws + 23068672);         // 32 MB: Q|K bf16 [8192][2048]
  ushort_t* VT = (ushort_t*)(ws + 23068672 + 33554432);  // 16 MB: VT [64*64][2048]

  cvt_bf16<<<8192, 256, 0, stream>>>(x, xb, 8192 * 1024 / 4);
  cvt_bf16<<<3072, 256, 0, stream>>>(Wq, wb, 3072 * 1024 / 4);
  gemm_qkv<<<64 * 24, 256, 0, stream>>>(xb, wb, qk, VT);
  attn2<<<64 * 8, 512, 0, stream>>>(qk, VT, out);
}